// Round 4
// baseline (114.295 us; speedup 1.0000x reference)
//
#include <hip/hip_runtime.h>

// Path signature, depth 4, D=8. Output layout (matches JAX flatten):
//   s1[8] | s2[64] (i*8+j) | s3[512] (i*64+j*8+k) | s4[4096] (i*512+j*64+k*8+l)
//
// Single fused kernel, 256 blocks:
//   phase 1: each block: signature of its 32-increment chunk (registers only)
//   phase 2: blocks 0..15 fold 16 chunk signatures each (Chen product),
//            register-pipelined 4-deep prefetch
//   phase 3: block 0 folds the 16 group results into d_out
// Cross-block handoff: release = __threadfence + relaxed agent atomic store;
// consumer = relaxed agent atomic poll (NO per-poll invalidate) + one
// agent acquire fence after the block barrier.
#define SIGLEN 4680
#define S1OFF 0
#define S2OFF 8
#define S3OFF 72
#define S4OFF 584
#define NCHUNK 256
#define NG 16
#define MAGIC 0x13572468u
#define MAXLEN 128

struct SigRegs {
  float s4[16];
  float a1, a2, a30, a31;
};

// One fold's B-operand, fully in named registers (~62 floats).
struct BBuf {
  float4 q2[4], q3[4], q4[4];
  float4 b1lo, b1hi;
  float b1i, b1j;
  float2 b1k;
  float b2own;
  float2 b2p, b3p;
};

__device__ __forceinline__ void loadB(BBuf& b, const float* __restrict__ B,
                                      int i_idx, int j_idx, int k0, int t) {
  const float4* q2 = (const float4*)(B + S2OFF + 16 * (t & 3));
  const float4* q3 = (const float4*)(B + S3OFF + 16 * (t & 31));
  const float4* q4 = (const float4*)(B + S4OFF + 16 * t);
#pragma unroll
  for (int r = 0; r < 4; ++r) { b.q2[r] = q2[r]; b.q3[r] = q3[r]; b.q4[r] = q4[r]; }
  b.b1lo = *(const float4*)(B + S1OFF);
  b.b1hi = *(const float4*)(B + S1OFF + 4);
  b.b1i = B[S1OFF + i_idx];
  b.b1j = B[S1OFF + j_idx];
  b.b1k = *(const float2*)(B + S1OFF + k0);
  b.b2own = B[S2OFF + (t >> 2)];
  b.b2p = *(const float2*)(B + S2OFF + ((2 * t) & 63));
  b.b3p = *(const float2*)(B + S3OFF + 2 * t);
}

// Full Chen left-fold: A <- A * B. (identical math to verified round-2 kernel)
//   c4 = a4 + b4 + a1(x)b3 + a2(x)b2 + a3(x)b1
//   c3 = a3 + b3 + a1(x)b2 + a2(x)b1 ; c2 = a2 + b2 + a1(x)b1 ; c1 = a1 + b1
__device__ __forceinline__ void foldB(SigRegs& A, const BBuf& b) {
  const float b1v[8] = {b.b1lo.x, b.b1lo.y, b.b1lo.z, b.b1lo.w,
                        b.b1hi.x, b.b1hi.y, b.b1hi.z, b.b1hi.w};
  const float* q2f = (const float*)b.q2;
  const float* q3f = (const float*)b.q3;
  const float* q4f = (const float*)b.q4;
#pragma unroll
  for (int e = 0; e < 16; ++e) {
    const float a3v = (e < 8) ? A.a30 : A.a31;
    A.s4[e] += q4f[e] + A.a1 * q3f[e] + A.a2 * q2f[e] + a3v * b1v[e & 7];
  }
  A.a30 += b.b3p.x + A.a1 * b.b2p.x + A.a2 * b.b1k.x;
  A.a31 += b.b3p.y + A.a1 * b.b2p.y + A.a2 * b.b1k.y;
  A.a2 += b.b2own + A.a1 * b.b1j;
  A.a1 += b.b1i;
}

__device__ __forceinline__ void load_sig(SigRegs& A, const float* __restrict__ B,
                                         int i_idx, int t) {
  const float4* p4 = (const float4*)(B + S4OFF + 16 * t);
#pragma unroll
  for (int r = 0; r < 4; ++r) {
    const float4 v = p4[r];
    A.s4[4 * r] = v.x; A.s4[4 * r + 1] = v.y; A.s4[4 * r + 2] = v.z; A.s4[4 * r + 3] = v.w;
  }
  A.a1 = B[S1OFF + i_idx];
  A.a2 = B[S2OFF + (t >> 2)];
  const float2 a3i = *(const float2*)(B + S3OFF + 2 * t);
  A.a30 = a3i.x; A.a31 = a3i.y;
}

__device__ __forceinline__ void store_sig(const SigRegs& A, float* __restrict__ o,
                                          int i_idx, int t) {
  if ((t & 31) == 0) o[S1OFF + i_idx] = A.a1;
  if ((t & 3) == 0) o[S2OFF + (t >> 2)] = A.a2;
  *(float2*)(o + S3OFF + 2 * t) = make_float2(A.a30, A.a31);
  float4* o4 = (float4*)(o + S4OFF + 16 * t);
#pragma unroll
  for (int r = 0; r < 4; ++r)
    o4[r] = make_float4(A.s4[4 * r], A.s4[4 * r + 1], A.s4[4 * r + 2], A.s4[4 * r + 3]);
}

// Relaxed poll (no per-iteration cache invalidate); acquire fence comes later.
__device__ __forceinline__ void wait_flag_relaxed(unsigned* f) {
  for (long i = 0; i < 200000000L; ++i) {
    if (__hip_atomic_load(f, __ATOMIC_RELAXED, __HIP_MEMORY_SCOPE_AGENT) == MAGIC)
      return;
  }
}

// Pipelined fold of sigs[1..NG-1] into A (A preloaded with sigs[0]).
// 4-deep register prefetch ring; fully unrolled -> all indices static.
__device__ __forceinline__ void fold_group(SigRegs& A, const float* __restrict__ base,
                                           int i_idx, int j_idx, int k0, int t) {
  BBuf b0, b1, b2, b3;
  loadB(b0, base + 1L * SIGLEN, i_idx, j_idx, k0, t);
  loadB(b1, base + 2L * SIGLEN, i_idx, j_idx, k0, t);
  loadB(b2, base + 3L * SIGLEN, i_idx, j_idx, k0, t);
  loadB(b3, base + 4L * SIGLEN, i_idx, j_idx, k0, t);
#pragma unroll
  for (int m = 1; m < NG; ++m) {
    const int slot = (m - 1) & 3;
    if (slot == 0) {
      foldB(A, b0);
      if (m + 4 < NG) loadB(b0, base + (long)(m + 4) * SIGLEN, i_idx, j_idx, k0, t);
    } else if (slot == 1) {
      foldB(A, b1);
      if (m + 4 < NG) loadB(b1, base + (long)(m + 4) * SIGLEN, i_idx, j_idx, k0, t);
    } else if (slot == 2) {
      foldB(A, b2);
      if (m + 4 < NG) loadB(b2, base + (long)(m + 4) * SIGLEN, i_idx, j_idx, k0, t);
    } else {
      foldB(A, b3);
      if (m + 4 < NG) loadB(b3, base + (long)(m + 4) * SIGLEN, i_idx, j_idx, k0, t);
    }
  }
}

__global__ __launch_bounds__(256, 1) void sig_fused(const float* __restrict__ path,
                                                    float* __restrict__ out,
                                                    float* __restrict__ ws,
                                                    int nInc) {
  float* partials = ws;                                  // NCHUNK * SIGLEN
  float* g2 = ws + (long)NCHUNK * SIGLEN;                // NG * SIGLEN
  unsigned* cflag = (unsigned*)(g2 + (long)NG * SIGLEN); // NCHUNK
  unsigned* gflag = cflag + NCHUNK;                      // NG

  const int t = threadIdx.x;
  const int c = blockIdx.x;
  const int i_idx = t >> 5;
  const int j_idx = (t >> 2) & 7;
  const int k0 = 2 * (t & 3);

  // ---------------- phase 1: chunk signature ----------------
  __shared__ float4 pl[(MAXLEN + 1) * 2];
  __shared__ float4 dv[MAXLEN * 2];
  const long start = ((long)c * nInc) / NCHUNK;
  const long end = ((long)(c + 1) * nInc) / NCHUNK;
  const int len = (int)(end - start);

  const float4* gp = (const float4*)(path + start * 8);
  for (int idx = t; idx < (len + 1) * 2; idx += 256) pl[idx] = gp[idx];
  __syncthreads();
  for (int idx = t; idx < len * 2; idx += 256) {
    float4 a = pl[idx + 2], b = pl[idx];
    dv[idx] = make_float4(a.x - b.x, a.y - b.y, a.z - b.z, a.w - b.w);
  }
  __syncthreads();
  const float* dvf = (const float*)dv;

  SigRegs A;
#pragma unroll
  for (int e = 0; e < 16; ++e) A.s4[e] = 0.f;
  A.a1 = 0.f; A.a2 = 0.f; A.a30 = 0.f; A.a31 = 0.f;

  for (int it = 0; it < len; ++it) {
    const float4 d0 = dv[it * 2], d1 = dv[it * 2 + 1];
    const float dxl[8] = {d0.x, d0.y, d0.z, d0.w, d1.x, d1.y, d1.z, d1.w};
    const float dxi = dvf[it * 8 + i_idx];
    const float dxj = dvf[it * 8 + j_idx];
    const float2 dkk = *(const float2*)(dvf + it * 8 + k0);

    const float inner = 0.5f * A.a2 + dxj * ((1.f / 6.f) * A.a1 + (1.f / 24.f) * dxi);
    const float c0 = A.a30 + dkk.x * inner;
    const float c1 = A.a31 + dkk.y * inner;
#pragma unroll
    for (int l = 0; l < 8; ++l) A.s4[l] += c0 * dxl[l];
#pragma unroll
    for (int l = 0; l < 8; ++l) A.s4[8 + l] += c1 * dxl[l];
    const float common3 = A.a2 + dxj * (0.5f * A.a1 + (1.f / 6.f) * dxi);
    A.a30 += common3 * dkk.x;
    A.a31 += common3 * dkk.y;
    A.a2 += dxj * (A.a1 + 0.5f * dxi);
    A.a1 += dxi;
  }

  store_sig(A, partials + (long)c * SIGLEN, i_idx, t);
  __syncthreads();  // all of this block's partial stores issued
  if (t == 0) {
    __threadfence();  // release: partial data visible at agent scope
    __hip_atomic_store(&cflag[c], MAGIC, __ATOMIC_RELAXED, __HIP_MEMORY_SCOPE_AGENT);
  }
  if (c >= NG) return;

  // ---------------- phase 2: fold 16 chunk sigs (blocks 0..15) ----------------
  if (t < NG) wait_flag_relaxed(&cflag[NG * c + t]);
  __syncthreads();
  __builtin_amdgcn_fence(__ATOMIC_ACQUIRE, "agent");  // one invalidate, not per poll

  const float* base = partials + (long)(NG * c) * SIGLEN;
  SigRegs G;
  load_sig(G, base, i_idx, t);
  fold_group(G, base, i_idx, j_idx, k0, t);

  store_sig(G, g2 + (long)c * SIGLEN, i_idx, t);
  __syncthreads();
  if (t == 0) {
    __threadfence();
    __hip_atomic_store(&gflag[c], MAGIC, __ATOMIC_RELAXED, __HIP_MEMORY_SCOPE_AGENT);
  }
  if (c != 0) return;

  // ---------------- phase 3: fold 16 group sigs (block 0) ----------------
  if (t < NG) wait_flag_relaxed(&gflag[t]);
  __syncthreads();
  __builtin_amdgcn_fence(__ATOMIC_ACQUIRE, "agent");

  SigRegs F;
  load_sig(F, g2, i_idx, t);
  fold_group(F, g2, i_idx, j_idx, k0, t);

  store_sig(F, out, i_idx, t);

  // reset flags for the next graph replay (kernel-end writeback publishes these)
  __syncthreads();
  for (int idx = t; idx < NCHUNK; idx += 256) cflag[idx] = 0u;
  if (t < NG) gflag[t] = 0u;
}

extern "C" void kernel_launch(void* const* d_in, const int* in_sizes, int n_in,
                              void* d_out, int out_size, void* d_ws, size_t ws_size,
                              hipStream_t stream) {
  const float* path = (const float*)d_in[0];
  float* out = (float*)d_out;
  const int L = in_sizes[0] / 8;
  const int nInc = L - 1;
  sig_fused<<<NCHUNK, 256, 0, stream>>>(path, out, (float*)d_ws, nInc);
}

// Round 5
// 103.128 us; speedup vs baseline: 1.1083x; 1.1083x over previous
//
#include <hip/hip_runtime.h>

// Path signature, depth 4, D=8. Output layout (matches JAX flatten):
//   s1[8] | s2[64] (i*8+j) | s3[512] (i*64+j*8+k) | s4[4096] (i*512+j*64+k*8+l)
//
// Single fused kernel, 256 blocks:
//   phase 1: each block: signature of its 32-increment chunk (registers only)
//   phase 2: blocks 0..15 fold 16 chunk signatures each (Chen product)
//   phase 3: block 0 folds the 16 group results into d_out
// Fold engine: B lower levels (s1..s3, 584 floats/sig) staged in LDS once per
// phase (16 sigs, 37 KB, one deep batch of loads); B.s4 own-slice via 4-deep
// register prefetch ring (64 VGPR). s3 stored with an XOR float4-chunk swizzle
// (c ^ ((c>>4)&7)) so the 16*(t&31) b128 read is 4-way instead of 16-way.
#define SIGLEN 4680
#define S1OFF 0
#define S2OFF 8
#define S3OFF 72
#define S4OFF 584
#define NCHUNK 256
#define NG 16
#define MAGIC 0x13572468u
#define MAXLEN 128
#define LROW 592  // LDS floats per staged sig (584 + 8 pad)

struct SigRegs { float s4[16]; float a1, a2, a30, a31; };

// s3 chunk swizzle: float4 chunk c (0..127) lives at float-offset
// S3OFF + 4*(c ^ ((c>>4)&7)). Involution, bijective, preserves 16B alignment.
__device__ __forceinline__ int s3off(int c) {
  return S3OFF + 4 * (c ^ ((c >> 4) & 7));
}

__device__ __forceinline__ void load_sig(SigRegs& A, const float* __restrict__ B,
                                         int i_idx, int t) {
  const float4* p4 = (const float4*)(B + S4OFF + 16 * t);
#pragma unroll
  for (int r = 0; r < 4; ++r) {
    const float4 v = p4[r];
    A.s4[4 * r] = v.x; A.s4[4 * r + 1] = v.y; A.s4[4 * r + 2] = v.z; A.s4[4 * r + 3] = v.w;
  }
  A.a1 = B[S1OFF + i_idx];
  A.a2 = B[S2OFF + (t >> 2)];
  const float2 a3i = *(const float2*)(B + S3OFF + 2 * t);
  A.a30 = a3i.x; A.a31 = a3i.y;
}

__device__ __forceinline__ void store_sig(const SigRegs& A, float* __restrict__ o,
                                          int i_idx, int t) {
  if ((t & 31) == 0) o[S1OFF + i_idx] = A.a1;
  if ((t & 3) == 0) o[S2OFF + (t >> 2)] = A.a2;
  *(float2*)(o + S3OFF + 2 * t) = make_float2(A.a30, A.a31);
  float4* o4 = (float4*)(o + S4OFF + 16 * t);
#pragma unroll
  for (int r = 0; r < 4; ++r)
    o4[r] = make_float4(A.s4[4 * r], A.s4[4 * r + 1], A.s4[4 * r + 2], A.s4[4 * r + 3]);
}

__device__ __forceinline__ void wait_flag_relaxed(unsigned* f) {
  for (long i = 0; i < 200000000L; ++i) {
    if (__hip_atomic_load(f, __ATOMIC_RELAXED, __HIP_MEMORY_SCOPE_AGENT) == MAGIC)
      return;
  }
}

// Chen left-fold A <- A*B; B lower levels from LDS row R, B.s4 own-slice from
// prefetched registers q4. Math identical to the verified round-2 kernel:
//   c4 = a4 + b4 + a1(x)b3 + a2(x)b2 + a3(x)b1
//   c3 = a3 + b3 + a1(x)b2 + a2(x)b1 ; c2 = a2 + b2 + a1(x)b1 ; c1 = a1 + b1
__device__ __forceinline__ void fold_lds(SigRegs& A, const float* __restrict__ R,
                                         const float4* __restrict__ q4,
                                         int i_idx, int j_idx, int k0, int t) {
  const float4 b1lo = *(const float4*)(R + S1OFF);
  const float4 b1hi = *(const float4*)(R + S1OFF + 4);
  const float b1v[8] = {b1lo.x, b1lo.y, b1lo.z, b1lo.w, b1hi.x, b1hi.y, b1hi.z, b1hi.w};
  const float b1i = R[S1OFF + i_idx];
  const float b1j = R[S1OFF + j_idx];
  const float2 b1k = *(const float2*)(R + S1OFF + k0);
  const float b2own = R[S2OFF + (t >> 2)];
  const float2 b2p = *(const float2*)(R + S2OFF + ((2 * t) & 63));
  const int c3 = t >> 1;  // chunk holding s3 elems {2t, 2t+1}
  const float2 b3p = *(const float2*)(R + s3off(c3) + 2 * (t & 1));
  float q2f[16], q3f[16];
  const float4* q2 = (const float4*)(R + S2OFF + 16 * (t & 3));
#pragma unroll
  for (int r = 0; r < 4; ++r) {
    const float4 v = q2[r];
    q2f[4 * r] = v.x; q2f[4 * r + 1] = v.y; q2f[4 * r + 2] = v.z; q2f[4 * r + 3] = v.w;
  }
#pragma unroll
  for (int r = 0; r < 4; ++r) {
    const float4 v = *(const float4*)(R + s3off(4 * (t & 31) + r));
    q3f[4 * r] = v.x; q3f[4 * r + 1] = v.y; q3f[4 * r + 2] = v.z; q3f[4 * r + 3] = v.w;
  }
  const float* q4f = (const float*)q4;
#pragma unroll
  for (int e = 0; e < 16; ++e) {
    const float a3v = (e < 8) ? A.a30 : A.a31;
    A.s4[e] += q4f[e] + A.a1 * q3f[e] + A.a2 * q2f[e] + a3v * b1v[e & 7];
  }
  A.a30 += b3p.x + A.a1 * b2p.x + A.a2 * b1k.x;
  A.a31 += b3p.y + A.a1 * b2p.y + A.a2 * b1k.y;
  A.a2 += b2own + A.a1 * b1j;
  A.a1 += b1i;
}

// Stage lower levels (584 floats = 146 float4 chunks) of NG sigs into LDS.
// s1+s2 chunks (r<18) linear; s3 chunks swizzled to match the read side.
__device__ __forceinline__ void stage_sigs(const float* __restrict__ gbase,
                                           float* __restrict__ lsig, int t) {
  for (int v = t; v < NG * 146; v += 256) {
    const int sig = v / 146;           // const-divisor -> mul_hi
    const int r = v - sig * 146;
    const float4 val = *(const float4*)(gbase + (long)sig * SIGLEN + 4 * r);
    const int off = (r < 18) ? 4 * r : s3off(r - 18);
    *(float4*)(lsig + sig * LROW + off) = val;
  }
}

__device__ __forceinline__ void loadq4(float4* dst, const float* __restrict__ gbase,
                                       int m, int t) {
  const float4* g = (const float4*)(gbase + (long)m * SIGLEN + S4OFF + 16 * t);
#pragma unroll
  for (int r = 0; r < 4; ++r) dst[r] = g[r];
}

// Fold sigs gbase[0..NG-1] -> outp. Assumes caller did the acquire fence.
__device__ __forceinline__ void fold16(const float* __restrict__ gbase,
                                       float* __restrict__ outp,
                                       float* __restrict__ lsig,
                                       int i_idx, int j_idx, int k0, int t) {
  SigRegs A;
  load_sig(A, gbase, i_idx, t);  // A = sig 0 (from global)
  float4 p0[4], p1[4], p2[4], p3[4];
  loadq4(p0, gbase, 1, t);
  loadq4(p1, gbase, 2, t);
  loadq4(p2, gbase, 3, t);
  loadq4(p3, gbase, 4, t);
  stage_sigs(gbase, lsig, t);  // deep batch; overlaps the prefetch latency
  __syncthreads();             // LDS staging complete
#pragma unroll
  for (int m = 1; m < NG; ++m) {  // fully unrolled -> static ring indices
    const int slot = (m - 1) & 3;
    if (slot == 0) {
      fold_lds(A, lsig + m * LROW, p0, i_idx, j_idx, k0, t);
      if (m + 4 < NG) loadq4(p0, gbase, m + 4, t);
    } else if (slot == 1) {
      fold_lds(A, lsig + m * LROW, p1, i_idx, j_idx, k0, t);
      if (m + 4 < NG) loadq4(p1, gbase, m + 4, t);
    } else if (slot == 2) {
      fold_lds(A, lsig + m * LROW, p2, i_idx, j_idx, k0, t);
      if (m + 4 < NG) loadq4(p2, gbase, m + 4, t);
    } else {
      fold_lds(A, lsig + m * LROW, p3, i_idx, j_idx, k0, t);
      if (m + 4 < NG) loadq4(p3, gbase, m + 4, t);
    }
  }
  store_sig(A, outp, i_idx, t);
}

__global__ __launch_bounds__(256, 1) void sig_fused(const float* __restrict__ path,
                                                    float* __restrict__ out,
                                                    float* __restrict__ ws,
                                                    int nInc) {
  float* partials = ws;                                  // NCHUNK * SIGLEN
  float* g2 = ws + (long)NCHUNK * SIGLEN;                // NG * SIGLEN
  unsigned* cflag = (unsigned*)(g2 + (long)NG * SIGLEN); // NCHUNK
  unsigned* gflag = cflag + NCHUNK;                      // NG

  __shared__ float4 pl[(MAXLEN + 1) * 2];
  __shared__ float4 dv[MAXLEN * 2];
  __shared__ float lsig[NG * LROW];  // 37888 B

  const int t = threadIdx.x;
  const int c = blockIdx.x;
  const int i_idx = t >> 5;
  const int j_idx = (t >> 2) & 7;
  const int k0 = 2 * (t & 3);

  // ---------------- phase 1: chunk signature ----------------
  const long start = ((long)c * nInc) / NCHUNK;
  const long end = ((long)(c + 1) * nInc) / NCHUNK;
  const int len = (int)(end - start);

  const float4* gp = (const float4*)(path + start * 8);
  for (int idx = t; idx < (len + 1) * 2; idx += 256) pl[idx] = gp[idx];
  __syncthreads();
  for (int idx = t; idx < len * 2; idx += 256) {
    float4 a = pl[idx + 2], b = pl[idx];
    dv[idx] = make_float4(a.x - b.x, a.y - b.y, a.z - b.z, a.w - b.w);
  }
  __syncthreads();
  const float* dvf = (const float*)dv;

  SigRegs A;
#pragma unroll
  for (int e = 0; e < 16; ++e) A.s4[e] = 0.f;
  A.a1 = 0.f; A.a2 = 0.f; A.a30 = 0.f; A.a31 = 0.f;

  for (int it = 0; it < len; ++it) {
    const float4 d0 = dv[it * 2], d1 = dv[it * 2 + 1];
    const float dxl[8] = {d0.x, d0.y, d0.z, d0.w, d1.x, d1.y, d1.z, d1.w};
    const float dxi = dvf[it * 8 + i_idx];
    const float dxj = dvf[it * 8 + j_idx];
    const float2 dkk = *(const float2*)(dvf + it * 8 + k0);

    const float inner = 0.5f * A.a2 + dxj * ((1.f / 6.f) * A.a1 + (1.f / 24.f) * dxi);
    const float c0 = A.a30 + dkk.x * inner;
    const float c1 = A.a31 + dkk.y * inner;
#pragma unroll
    for (int l = 0; l < 8; ++l) A.s4[l] += c0 * dxl[l];
#pragma unroll
    for (int l = 0; l < 8; ++l) A.s4[8 + l] += c1 * dxl[l];
    const float common3 = A.a2 + dxj * (0.5f * A.a1 + (1.f / 6.f) * dxi);
    A.a30 += common3 * dkk.x;
    A.a31 += common3 * dkk.y;
    A.a2 += dxj * (A.a1 + 0.5f * dxi);
    A.a1 += dxi;
  }

  store_sig(A, partials + (long)c * SIGLEN, i_idx, t);
  __syncthreads();  // all of this block's partial stores completed (vmcnt drain)
  if (t == 0) {
    __threadfence();  // release: partials visible at agent scope
    __hip_atomic_store(&cflag[c], MAGIC, __ATOMIC_RELAXED, __HIP_MEMORY_SCOPE_AGENT);
  }
  if (c >= NG) return;

  // ---------------- phase 2: fold 16 chunk sigs (blocks 0..15) ----------------
  if (t < NG) wait_flag_relaxed(&cflag[NG * c + t]);
  __syncthreads();
  __builtin_amdgcn_fence(__ATOMIC_ACQUIRE, "agent");  // one invalidate, not per poll

  fold16(partials + (long)(NG * c) * SIGLEN, g2 + (long)c * SIGLEN, lsig,
         i_idx, j_idx, k0, t);
  __syncthreads();
  if (t == 0) {
    __threadfence();
    __hip_atomic_store(&gflag[c], MAGIC, __ATOMIC_RELAXED, __HIP_MEMORY_SCOPE_AGENT);
  }
  if (c != 0) return;

  // ---------------- phase 3: fold 16 group sigs (block 0) ----------------
  if (t < NG) wait_flag_relaxed(&gflag[t]);
  __syncthreads();
  __builtin_amdgcn_fence(__ATOMIC_ACQUIRE, "agent");

  fold16(g2, out, lsig, i_idx, j_idx, k0, t);

  // reset flags for the next graph replay (block 0 finishes last; kernel-end
  // writeback publishes these)
  __syncthreads();
  for (int idx = t; idx < NCHUNK; idx += 256) cflag[idx] = 0u;
  if (t < NG) gflag[t] = 0u;
}

extern "C" void kernel_launch(void* const* d_in, const int* in_sizes, int n_in,
                              void* d_out, int out_size, void* d_ws, size_t ws_size,
                              hipStream_t stream) {
  const float* path = (const float*)d_in[0];
  float* out = (float*)d_out;
  const int L = in_sizes[0] / 8;
  const int nInc = L - 1;
  sig_fused<<<NCHUNK, 256, 0, stream>>>(path, out, (float*)d_ws, nInc);
}

// Round 6
// 37.472 us; speedup vs baseline: 3.0502x; 2.7521x over previous
//
#include <hip/hip_runtime.h>

// Path signature, depth 4, D=8. Output layout (matches JAX flatten):
//   s1[8] | s2[64] (i*8+j) | s3[512] (i*64+j*8+k) | s4[4096] (i*512+j*64+k*8+l)
//
// Single fused kernel, 256 blocks:
//   phase 1: each block: signature of its 32-increment chunk (registers only)
//   phase 2: blocks 0..15 fold 16 chunk signatures each (Chen product)
//   phase 3: block 0 folds the 16 group results into d_out
// Fold engine: B lower levels (s1..s3) staged in LDS once per phase (16 sigs,
// 37 KB, one static batch of loads); B.s4 own-slice via a 2-deep register
// double-buffer (32 VGPR). Fold loop NOT unrolled (live-set control; round-4/5
// spilled to scratch from a 4-deep ring + full unroll: VGPR=256, +10MB writes).
#define SIGLEN 4680
#define S1OFF 0
#define S2OFF 8
#define S3OFF 72
#define S4OFF 584
#define NCHUNK 256
#define NG 16
#define MAGIC 0x13572468u
#define MAXLEN 128
#define LROW 592  // LDS floats per staged sig (584 + 8 pad)

struct SigRegs { float s4[16]; float a1, a2, a30, a31; };

// s3 chunk swizzle: float4 chunk c (0..127) lives at float-offset
// S3OFF + 4*(c ^ ((c>>4)&7)). Involution, bijective, 16B-aligned. Makes the
// 16*(t&31)-pattern b128 reads 4-way instead of 16-way conflicted.
__device__ __forceinline__ int s3off(int c) {
  return S3OFF + 4 * (c ^ ((c >> 4) & 7));
}

__device__ __forceinline__ void load_sig(SigRegs& A, const float* __restrict__ B,
                                         int i_idx, int t) {
  const float4* p4 = (const float4*)(B + S4OFF + 16 * t);
#pragma unroll
  for (int r = 0; r < 4; ++r) {
    const float4 v = p4[r];
    A.s4[4 * r] = v.x; A.s4[4 * r + 1] = v.y; A.s4[4 * r + 2] = v.z; A.s4[4 * r + 3] = v.w;
  }
  A.a1 = B[S1OFF + i_idx];
  A.a2 = B[S2OFF + (t >> 2)];
  const float2 a3i = *(const float2*)(B + S3OFF + 2 * t);
  A.a30 = a3i.x; A.a31 = a3i.y;
}

__device__ __forceinline__ void store_sig(const SigRegs& A, float* __restrict__ o,
                                          int i_idx, int t) {
  if ((t & 31) == 0) o[S1OFF + i_idx] = A.a1;
  if ((t & 3) == 0) o[S2OFF + (t >> 2)] = A.a2;
  *(float2*)(o + S3OFF + 2 * t) = make_float2(A.a30, A.a31);
  float4* o4 = (float4*)(o + S4OFF + 16 * t);
#pragma unroll
  for (int r = 0; r < 4; ++r)
    o4[r] = make_float4(A.s4[4 * r], A.s4[4 * r + 1], A.s4[4 * r + 2], A.s4[4 * r + 3]);
}

__device__ __forceinline__ void wait_flag_relaxed(unsigned* f) {
  for (long i = 0; i < 200000000L; ++i) {
    if (__hip_atomic_load(f, __ATOMIC_RELAXED, __HIP_MEMORY_SCOPE_AGENT) == MAGIC)
      return;
  }
}

// Chen left-fold A <- A*B; B lower levels from LDS row R, B.s4 own-slice from
// registers q4. Math identical to the verified round-2 kernel:
//   c4 = a4 + b4 + a1(x)b3 + a2(x)b2 + a3(x)b1
//   c3 = a3 + b3 + a1(x)b2 + a2(x)b1 ; c2 = a2 + b2 + a1(x)b1 ; c1 = a1 + b1
__device__ __forceinline__ void fold_lds(SigRegs& A, const float* __restrict__ R,
                                         const float4* __restrict__ q4,
                                         int i_idx, int j_idx, int k0, int t) {
  const float4 b1lo = *(const float4*)(R + S1OFF);
  const float4 b1hi = *(const float4*)(R + S1OFF + 4);
  const float b1i = R[S1OFF + i_idx];
  const float b1j = R[S1OFF + j_idx];
  const float2 b1k = *(const float2*)(R + S1OFF + k0);
  const float b2own = R[S2OFF + (t >> 2)];
  const float2 b2p = *(const float2*)(R + S2OFF + ((2 * t) & 63));
  const float2 b3p = *(const float2*)(R + s3off(t >> 1) + 2 * (t & 1));
  const float4* q2 = (const float4*)(R + S2OFF + 16 * (t & 3));
#pragma unroll
  for (int r = 0; r < 4; ++r) {
    const float4 v2 = q2[r];
    const float4 v3 = *(const float4*)(R + s3off(4 * (t & 31) + r));
    const float4 v4 = q4[r];
    const float a3v = (r < 2) ? A.a30 : A.a31;   // e<8 -> a30
    const float4 bb = (r & 1) ? b1hi : b1lo;     // b1v[(4r+c)&7]
    A.s4[4 * r + 0] += v4.x + A.a1 * v3.x + A.a2 * v2.x + a3v * bb.x;
    A.s4[4 * r + 1] += v4.y + A.a1 * v3.y + A.a2 * v2.y + a3v * bb.y;
    A.s4[4 * r + 2] += v4.z + A.a1 * v3.z + A.a2 * v2.z + a3v * bb.z;
    A.s4[4 * r + 3] += v4.w + A.a1 * v3.w + A.a2 * v2.w + a3v * bb.w;
  }
  A.a30 += b3p.x + A.a1 * b2p.x + A.a2 * b1k.x;
  A.a31 += b3p.y + A.a1 * b2p.y + A.a2 * b1k.y;
  A.a2 += b2own + A.a1 * b1j;
  A.a1 += b1i;
}

__device__ __forceinline__ void loadq4(float4* dst, const float* __restrict__ gbase,
                                       int m, int t) {
  const float4* g = (const float4*)(gbase + (long)m * SIGLEN + S4OFF + 16 * t);
#pragma unroll
  for (int r = 0; r < 4; ++r) dst[r] = g[r];
}

// Fold sigs gbase[0..NG-1] -> outp. Caller did the acquire fence.
__device__ __forceinline__ void fold16(const float* __restrict__ gbase,
                                       float* __restrict__ outp,
                                       float* __restrict__ lsig,
                                       int i_idx, int j_idx, int k0, int t) {
  SigRegs A;
  load_sig(A, gbase, i_idx, t);  // A = sig 0 (from global)
  float4 qA[4], qB[4];
  loadq4(qA, gbase, 1, t);
  loadq4(qB, gbase, 2, t);

  // Stage lower levels (146 float4 chunks x NG sigs) into LDS: static 10-slot
  // batch per thread (issue all loads, then all LDS writes). s3 swizzled.
  {
    float4 vals[10];
#pragma unroll
    for (int s = 0; s < 10; ++s) {
      const int v = t + 256 * s;
      const int vc = (v < NG * 146) ? v : (NG * 146 - 1);
      const int sig = vc / 146;
      const int r = vc - sig * 146;
      vals[s] = *(const float4*)(gbase + (long)sig * SIGLEN + 4 * r);
    }
#pragma unroll
    for (int s = 0; s < 10; ++s) {
      const int v = t + 256 * s;
      if (v < NG * 146) {
        const int sig = v / 146;
        const int r = v - sig * 146;
        const int off = (r < 18) ? 4 * r : s3off(r - 18);
        *(float4*)(lsig + sig * LROW + off) = vals[s];
      }
    }
  }
  __syncthreads();  // LDS staging complete

  // 15 folds: runtime loop, 2-wide software pipeline, named double-buffer.
#pragma unroll 1
  for (int m = 1; m < NG - 2; m += 2) {  // m = 1,3,...,13
    fold_lds(A, lsig + m * LROW, qA, i_idx, j_idx, k0, t);
    loadq4(qA, gbase, m + 2, t);
    fold_lds(A, lsig + (m + 1) * LROW, qB, i_idx, j_idx, k0, t);
    if (m + 3 < NG) loadq4(qB, gbase, m + 3, t);
  }
  fold_lds(A, lsig + (NG - 1) * LROW, qA, i_idx, j_idx, k0, t);  // m = 15
  store_sig(A, outp, i_idx, t);
}

__global__ __launch_bounds__(256, 1) void sig_fused(const float* __restrict__ path,
                                                    float* __restrict__ out,
                                                    float* __restrict__ ws,
                                                    int nInc) {
  float* partials = ws;                                  // NCHUNK * SIGLEN
  float* g2 = ws + (long)NCHUNK * SIGLEN;                // NG * SIGLEN
  unsigned* cflag = (unsigned*)(g2 + (long)NG * SIGLEN); // NCHUNK
  unsigned* gflag = cflag + NCHUNK;                      // NG

  __shared__ float4 pl[(MAXLEN + 1) * 2];
  __shared__ float4 dv[MAXLEN * 2];
  __shared__ float lsig[NG * LROW];  // 37888 B

  const int t = threadIdx.x;
  const int c = blockIdx.x;
  const int i_idx = t >> 5;
  const int j_idx = (t >> 2) & 7;
  const int k0 = 2 * (t & 3);

  // ---------------- phase 1: chunk signature ----------------
  const long start = ((long)c * nInc) / NCHUNK;
  const long end = ((long)(c + 1) * nInc) / NCHUNK;
  const int len = (int)(end - start);

  const float4* gp = (const float4*)(path + start * 8);
  for (int idx = t; idx < (len + 1) * 2; idx += 256) pl[idx] = gp[idx];
  __syncthreads();
  for (int idx = t; idx < len * 2; idx += 256) {
    float4 a = pl[idx + 2], b = pl[idx];
    dv[idx] = make_float4(a.x - b.x, a.y - b.y, a.z - b.z, a.w - b.w);
  }
  __syncthreads();
  const float* dvf = (const float*)dv;

  SigRegs A;
#pragma unroll
  for (int e = 0; e < 16; ++e) A.s4[e] = 0.f;
  A.a1 = 0.f; A.a2 = 0.f; A.a30 = 0.f; A.a31 = 0.f;

  for (int it = 0; it < len; ++it) {
    const float4 d0 = dv[it * 2], d1 = dv[it * 2 + 1];
    const float dxl[8] = {d0.x, d0.y, d0.z, d0.w, d1.x, d1.y, d1.z, d1.w};
    const float dxi = dvf[it * 8 + i_idx];
    const float dxj = dvf[it * 8 + j_idx];
    const float2 dkk = *(const float2*)(dvf + it * 8 + k0);

    const float inner = 0.5f * A.a2 + dxj * ((1.f / 6.f) * A.a1 + (1.f / 24.f) * dxi);
    const float c0 = A.a30 + dkk.x * inner;
    const float c1 = A.a31 + dkk.y * inner;
#pragma unroll
    for (int l = 0; l < 8; ++l) A.s4[l] += c0 * dxl[l];
#pragma unroll
    for (int l = 0; l < 8; ++l) A.s4[8 + l] += c1 * dxl[l];
    const float common3 = A.a2 + dxj * (0.5f * A.a1 + (1.f / 6.f) * dxi);
    A.a30 += common3 * dkk.x;
    A.a31 += common3 * dkk.y;
    A.a2 += dxj * (A.a1 + 0.5f * dxi);
    A.a1 += dxi;
  }

  store_sig(A, partials + (long)c * SIGLEN, i_idx, t);
  __syncthreads();  // all of this block's partial stores issued
  if (t == 0) {
    __threadfence();  // release: partials visible at agent scope
    __hip_atomic_store(&cflag[c], MAGIC, __ATOMIC_RELAXED, __HIP_MEMORY_SCOPE_AGENT);
  }
  if (c >= NG) return;

  // ---------------- phase 2: fold 16 chunk sigs (blocks 0..15) ----------------
  if (t < NG) wait_flag_relaxed(&cflag[NG * c + t]);
  __syncthreads();
  __builtin_amdgcn_fence(__ATOMIC_ACQUIRE, "agent");  // one invalidate, not per poll

  fold16(partials + (long)(NG * c) * SIGLEN, g2 + (long)c * SIGLEN, lsig,
         i_idx, j_idx, k0, t);
  __syncthreads();  // also guards lsig reuse by phase 3 in block 0
  if (t == 0) {
    __threadfence();
    __hip_atomic_store(&gflag[c], MAGIC, __ATOMIC_RELAXED, __HIP_MEMORY_SCOPE_AGENT);
  }
  if (c != 0) return;

  // ---------------- phase 3: fold 16 group sigs (block 0) ----------------
  if (t < NG) wait_flag_relaxed(&gflag[t]);
  __syncthreads();
  __builtin_amdgcn_fence(__ATOMIC_ACQUIRE, "agent");

  fold16(g2, out, lsig, i_idx, j_idx, k0, t);

  // reset flags for the next graph replay (kernel-end writeback publishes these)
  __syncthreads();
  for (int idx = t; idx < NCHUNK; idx += 256) cflag[idx] = 0u;
  if (t < NG) gflag[t] = 0u;
}

extern "C" void kernel_launch(void* const* d_in, const int* in_sizes, int n_in,
                              void* d_out, int out_size, void* d_ws, size_t ws_size,
                              hipStream_t stream) {
  const float* path = (const float*)d_in[0];
  float* out = (float*)d_out;
  const int L = in_sizes[0] / 8;
  const int nInc = L - 1;
  sig_fused<<<NCHUNK, 256, 0, stream>>>(path, out, (float*)d_ws, nInc);
}

// Round 7
// 28.425 us; speedup vs baseline: 4.0210x; 1.3183x over previous
//
#include <hip/hip_runtime.h>

// Path signature, depth 4, D=8. Output layout (matches JAX flatten):
//   s1[8] | s2[64] (i*8+j) | s3[512] (i*64+j*8+k) | s4[4096] (i*512+j*64+k*8+l)
//
// Three kernels (kernel boundaries = free cross-XCD coherence; round-6's fused
// single-kernel used flag+fence handoffs and lost ~20us to L2 wb/inv + polling):
//   k1: 256 blocks, each computes the signature of its ~32-increment chunk
//       (state fully thread-private in registers, barrier-free scan)
//   k2: 16 blocks, each folds 16 chunk sigs (Chen product, LDS-staged B)
//   k3: 1 block, folds the 16 group sigs into d_out
// Fold engine (validated round 6): B lower levels (s1..s3) staged in LDS once
// per fold phase (16 sigs, 37 KB, one static batch); B.s4 own-slice via 2-deep
// register double-buffer. Fold loop NOT unrolled (live-set control; a 4-deep
// ring + full unroll spilled: VGPR=256, +10MB scratch writes, 3x slower).
#define SIGLEN 4680
#define S1OFF 0
#define S2OFF 8
#define S3OFF 72
#define S4OFF 584
#define NCHUNK 256
#define NG 16
#define MAXLEN 128
#define LROW 592  // LDS floats per staged sig (584 + 8 pad)

struct SigRegs { float s4[16]; float a1, a2, a30, a31; };

// s3 chunk swizzle: float4 chunk c (0..127) lives at float-offset
// S3OFF + 4*(c ^ ((c>>4)&7)). Involution, bijective, 16B-aligned. Makes the
// 16*(t&31)-pattern b128 reads 4-way instead of 16-way conflicted.
__device__ __forceinline__ int s3off(int c) {
  return S3OFF + 4 * (c ^ ((c >> 4) & 7));
}

__device__ __forceinline__ void load_sig(SigRegs& A, const float* __restrict__ B,
                                         int i_idx, int t) {
  const float4* p4 = (const float4*)(B + S4OFF + 16 * t);
#pragma unroll
  for (int r = 0; r < 4; ++r) {
    const float4 v = p4[r];
    A.s4[4 * r] = v.x; A.s4[4 * r + 1] = v.y; A.s4[4 * r + 2] = v.z; A.s4[4 * r + 3] = v.w;
  }
  A.a1 = B[S1OFF + i_idx];
  A.a2 = B[S2OFF + (t >> 2)];
  const float2 a3i = *(const float2*)(B + S3OFF + 2 * t);
  A.a30 = a3i.x; A.a31 = a3i.y;
}

__device__ __forceinline__ void store_sig(const SigRegs& A, float* __restrict__ o,
                                          int i_idx, int t) {
  if ((t & 31) == 0) o[S1OFF + i_idx] = A.a1;
  if ((t & 3) == 0) o[S2OFF + (t >> 2)] = A.a2;
  *(float2*)(o + S3OFF + 2 * t) = make_float2(A.a30, A.a31);
  float4* o4 = (float4*)(o + S4OFF + 16 * t);
#pragma unroll
  for (int r = 0; r < 4; ++r)
    o4[r] = make_float4(A.s4[4 * r], A.s4[4 * r + 1], A.s4[4 * r + 2], A.s4[4 * r + 3]);
}

// Chen left-fold A <- A*B; B lower levels from LDS row R, B.s4 own-slice from
// registers q4. Math identical to the verified round-2 kernel:
//   c4 = a4 + b4 + a1(x)b3 + a2(x)b2 + a3(x)b1
//   c3 = a3 + b3 + a1(x)b2 + a2(x)b1 ; c2 = a2 + b2 + a1(x)b1 ; c1 = a1 + b1
__device__ __forceinline__ void fold_lds(SigRegs& A, const float* __restrict__ R,
                                         const float4* __restrict__ q4,
                                         int i_idx, int j_idx, int k0, int t) {
  const float4 b1lo = *(const float4*)(R + S1OFF);
  const float4 b1hi = *(const float4*)(R + S1OFF + 4);
  const float b1i = R[S1OFF + i_idx];
  const float b1j = R[S1OFF + j_idx];
  const float2 b1k = *(const float2*)(R + S1OFF + k0);
  const float b2own = R[S2OFF + (t >> 2)];
  const float2 b2p = *(const float2*)(R + S2OFF + ((2 * t) & 63));
  const float2 b3p = *(const float2*)(R + s3off(t >> 1) + 2 * (t & 1));
  const float4* q2 = (const float4*)(R + S2OFF + 16 * (t & 3));
#pragma unroll
  for (int r = 0; r < 4; ++r) {
    const float4 v2 = q2[r];
    const float4 v3 = *(const float4*)(R + s3off(4 * (t & 31) + r));
    const float4 v4 = q4[r];
    const float a3v = (r < 2) ? A.a30 : A.a31;   // e<8 -> a30
    const float4 bb = (r & 1) ? b1hi : b1lo;     // b1v[(4r+c)&7]
    A.s4[4 * r + 0] += v4.x + A.a1 * v3.x + A.a2 * v2.x + a3v * bb.x;
    A.s4[4 * r + 1] += v4.y + A.a1 * v3.y + A.a2 * v2.y + a3v * bb.y;
    A.s4[4 * r + 2] += v4.z + A.a1 * v3.z + A.a2 * v2.z + a3v * bb.z;
    A.s4[4 * r + 3] += v4.w + A.a1 * v3.w + A.a2 * v2.w + a3v * bb.w;
  }
  A.a30 += b3p.x + A.a1 * b2p.x + A.a2 * b1k.x;
  A.a31 += b3p.y + A.a1 * b2p.y + A.a2 * b1k.y;
  A.a2 += b2own + A.a1 * b1j;
  A.a1 += b1i;
}

__device__ __forceinline__ void loadq4(float4* dst, const float* __restrict__ gbase,
                                       int m, int t) {
  const float4* g = (const float4*)(gbase + (long)m * SIGLEN + S4OFF + 16 * t);
#pragma unroll
  for (int r = 0; r < 4; ++r) dst[r] = g[r];
}

// Fold sigs gbase[0..NG-1] -> outp.
__device__ __forceinline__ void fold16(const float* __restrict__ gbase,
                                       float* __restrict__ outp,
                                       float* __restrict__ lsig,
                                       int i_idx, int j_idx, int k0, int t) {
  SigRegs A;
  load_sig(A, gbase, i_idx, t);  // A = sig 0 (from global)
  float4 qA[4], qB[4];
  loadq4(qA, gbase, 1, t);
  loadq4(qB, gbase, 2, t);

  // Stage lower levels (146 float4 chunks x NG sigs) into LDS: static 10-slot
  // batch per thread (issue all loads, then all LDS writes). s3 swizzled.
  {
    float4 vals[10];
#pragma unroll
    for (int s = 0; s < 10; ++s) {
      const int v = t + 256 * s;
      const int vc = (v < NG * 146) ? v : (NG * 146 - 1);
      const int sig = vc / 146;
      const int r = vc - sig * 146;
      vals[s] = *(const float4*)(gbase + (long)sig * SIGLEN + 4 * r);
    }
#pragma unroll
    for (int s = 0; s < 10; ++s) {
      const int v = t + 256 * s;
      if (v < NG * 146) {
        const int sig = v / 146;
        const int r = v - sig * 146;
        const int off = (r < 18) ? 4 * r : s3off(r - 18);
        *(float4*)(lsig + sig * LROW + off) = vals[s];
      }
    }
  }
  __syncthreads();  // LDS staging complete

  // 15 folds: runtime loop, 2-wide software pipeline, named double-buffer.
#pragma unroll 1
  for (int m = 1; m < NG - 2; m += 2) {  // m = 1,3,...,13
    fold_lds(A, lsig + m * LROW, qA, i_idx, j_idx, k0, t);
    loadq4(qA, gbase, m + 2, t);
    fold_lds(A, lsig + (m + 1) * LROW, qB, i_idx, j_idx, k0, t);
    if (m + 3 < NG) loadq4(qB, gbase, m + 3, t);
  }
  fold_lds(A, lsig + (NG - 1) * LROW, qA, i_idx, j_idx, k0, t);  // m = 15
  store_sig(A, outp, i_idx, t);
}

// ------------------------- kernel 1: chunk signatures -------------------------
__global__ __launch_bounds__(256, 1) void sig_chunk(const float* __restrict__ path,
                                                    float* __restrict__ partials,
                                                    int nInc) {
  __shared__ float4 pl[(MAXLEN + 1) * 2];
  __shared__ float4 dv[MAXLEN * 2];
  const int t = threadIdx.x;
  const int c = blockIdx.x;
  const int i_idx = t >> 5;
  const int j_idx = (t >> 2) & 7;
  const int k0 = 2 * (t & 3);

  const long start = ((long)c * nInc) / NCHUNK;
  const long end = ((long)(c + 1) * nInc) / NCHUNK;
  const int len = (int)(end - start);

  const float4* gp = (const float4*)(path + start * 8);
  for (int idx = t; idx < (len + 1) * 2; idx += 256) pl[idx] = gp[idx];
  __syncthreads();
  for (int idx = t; idx < len * 2; idx += 256) {
    float4 a = pl[idx + 2], b = pl[idx];
    dv[idx] = make_float4(a.x - b.x, a.y - b.y, a.z - b.z, a.w - b.w);
  }
  __syncthreads();
  const float* dvf = (const float*)dv;

  SigRegs A;
#pragma unroll
  for (int e = 0; e < 16; ++e) A.s4[e] = 0.f;
  A.a1 = 0.f; A.a2 = 0.f; A.a30 = 0.f; A.a31 = 0.f;

  for (int it = 0; it < len; ++it) {
    const float4 d0 = dv[it * 2], d1 = dv[it * 2 + 1];
    const float dxl[8] = {d0.x, d0.y, d0.z, d0.w, d1.x, d1.y, d1.z, d1.w};
    const float dxi = dvf[it * 8 + i_idx];
    const float dxj = dvf[it * 8 + j_idx];
    const float2 dkk = *(const float2*)(dvf + it * 8 + k0);

    const float inner = 0.5f * A.a2 + dxj * ((1.f / 6.f) * A.a1 + (1.f / 24.f) * dxi);
    const float c0 = A.a30 + dkk.x * inner;
    const float c1 = A.a31 + dkk.y * inner;
#pragma unroll
    for (int l = 0; l < 8; ++l) A.s4[l] += c0 * dxl[l];
#pragma unroll
    for (int l = 0; l < 8; ++l) A.s4[8 + l] += c1 * dxl[l];
    const float common3 = A.a2 + dxj * (0.5f * A.a1 + (1.f / 6.f) * dxi);
    A.a30 += common3 * dkk.x;
    A.a31 += common3 * dkk.y;
    A.a2 += dxj * (A.a1 + 0.5f * dxi);
    A.a1 += dxi;
  }

  store_sig(A, partials + (long)c * SIGLEN, i_idx, t);
}

// ------------------- kernel 2: fold 16 chunk sigs per block -------------------
__global__ __launch_bounds__(256, 1) void sig_fold16(const float* __restrict__ in,
                                                     float* __restrict__ outp) {
  __shared__ float lsig[NG * LROW];  // 37888 B
  const int t = threadIdx.x;
  const int b = blockIdx.x;
  const int i_idx = t >> 5;
  const int j_idx = (t >> 2) & 7;
  const int k0 = 2 * (t & 3);
  fold16(in + (long)(NG * b) * SIGLEN, outp + (long)b * SIGLEN, lsig,
         i_idx, j_idx, k0, t);
}

// ---------------------- kernel 3: final fold of 16 sigs ----------------------
__global__ __launch_bounds__(256, 1) void sig_fold_final(const float* __restrict__ in,
                                                         float* __restrict__ outp) {
  __shared__ float lsig[NG * LROW];
  const int t = threadIdx.x;
  const int i_idx = t >> 5;
  const int j_idx = (t >> 2) & 7;
  const int k0 = 2 * (t & 3);
  fold16(in, outp, lsig, i_idx, j_idx, k0, t);
}

extern "C" void kernel_launch(void* const* d_in, const int* in_sizes, int n_in,
                              void* d_out, int out_size, void* d_ws, size_t ws_size,
                              hipStream_t stream) {
  const float* path = (const float*)d_in[0];
  float* out = (float*)d_out;
  const int L = in_sizes[0] / 8;
  const int nInc = L - 1;

  float* partials = (float*)d_ws;                    // NCHUNK * SIGLEN floats
  float* g2 = partials + (long)NCHUNK * SIGLEN;      // NG * SIGLEN floats

  sig_chunk<<<NCHUNK, 256, 0, stream>>>(path, partials, nInc);
  sig_fold16<<<NG, 256, 0, stream>>>(partials, g2);
  sig_fold_final<<<1, 256, 0, stream>>>(g2, out);
}